// Round 9
// baseline (148.376 us; speedup 1.0000x reference)
//
#include <hip/hip_runtime.h>
#include <hip/hip_bf16.h>
#include <hip/hip_fp16.h>

typedef _Float16 f16x8 __attribute__((ext_vector_type(8)));
typedef _Float16 f16x4 __attribute__((ext_vector_type(4)));
typedef _Float16 f16x2 __attribute__((ext_vector_type(2)));
typedef float f32x4 __attribute__((ext_vector_type(4)));
typedef float f32x16 __attribute__((ext_vector_type(16)));
typedef unsigned int u32x4 __attribute__((ext_vector_type(4)));

#define MFMA16(a, b, c) __builtin_amdgcn_mfma_f32_16x16x32_f16(a, b, c, 0, 0, 0)
#define MFMA32(a, b, c) __builtin_amdgcn_mfma_f32_32x32x16_f16(a, b, c, 0, 0, 0)

// log2(e) / sqrt(1024)
#define C1 0.045084220027780106f

// ---------------------------------------------------------------------------
// convert f32 -> fp16 for Q, K, Wq, Wk, Wv into one contiguous ws region
// ---------------------------------------------------------------------------
__global__ void cvt_all(const float* __restrict__ Q, const float* __restrict__ K,
                        const float* __restrict__ Wq, const float* __restrict__ Wk,
                        const float* __restrict__ Wv, _Float16* __restrict__ dst) {
    int i = blockIdx.x * blockDim.x + threadIdx.x;  // i indexes groups of 8 f32
    const float* s;
    int off;
    if (i < 524288)       { s = Q;  off = 0;       }
    else if (i < 1048576) { s = K;  off = 524288;  }
    else if (i < 1179648) { s = Wq; off = 1048576; }
    else if (i < 1310720) { s = Wk; off = 1179648; }
    else                  { s = Wv; off = 1310720; }
    int j = i - off;
    float4 a = ((const float4*)s)[2 * j];
    float4 b = ((const float4*)s)[2 * j + 1];
    f16x8 h;
    h[0] = (_Float16)a.x; h[1] = (_Float16)a.y; h[2] = (_Float16)a.z; h[3] = (_Float16)a.w;
    h[4] = (_Float16)b.x; h[5] = (_Float16)b.y; h[6] = (_Float16)b.z; h[7] = (_Float16)b.w;
    ((f16x8*)dst)[i] = h;
}

// ---------------------------------------------------------------------------
// projection GEMM: C[m,n] = A[m,:]·W[n,:] + bias[n]
// Outputs in attention-fragment-tiled layouts (1KB coalesced pages):
//  qT[head][qt 32][dc 4][q5 32][hi 2][j 8]
//  kT[head][w 8][kt 4][dc 4][q5 32][hi 2][j 8]
//  vT[head][w 8][kt 4][dh 2][ks 2][q5 32][hi 2][j 8]
// ---------------------------------------------------------------------------
__device__ __forceinline__ void gl_lds16(const void* g, void* l) {
    __builtin_amdgcn_global_load_lds(
        (const __attribute__((address_space(1))) void*)g,
        (__attribute__((address_space(3))) void*)l, 16, 0, 0);
}

__global__ __launch_bounds__(256) void proj_gemm(
    const _Float16* __restrict__ Qh, const _Float16* __restrict__ Kh,
    const _Float16* __restrict__ Wqh, const _Float16* __restrict__ Wkh,
    const _Float16* __restrict__ Wvh,
    const float* __restrict__ bq, const float* __restrict__ bk,
    const float* __restrict__ bv,
    _Float16* __restrict__ qT, _Float16* __restrict__ kT,
    _Float16* __restrict__ vT) {
    const int z = blockIdx.z;
    const _Float16* A = (z == 0) ? Qh : Kh;
    const _Float16* W = (z == 0) ? Wqh : (z == 1 ? Wkh : Wvh);
    const float* bias = (z == 0) ? bq : (z == 1 ? bk : bv);

    __shared__ __align__(16) _Float16 At[128 * 32];
    __shared__ __align__(16) _Float16 Bt[128 * 32];

    const int tid = threadIdx.x;
    const int w = tid >> 6, lane = tid & 63;
    const int g = lane >> 4, c = lane & 15;
    const int m0 = blockIdx.x * 128, n0 = blockIdx.y * 128;
    const int wm = (w & 1) * 64, wn = (w >> 1) * 64;
    const int srow = w * 32 + (lane >> 2);
    const int scol = (lane & 3) * 8;  // in halves

    f32x4 acc[4][4] = {};

    for (int k0 = 0; k0 < 1024; k0 += 32) {
        __syncthreads();
#pragma unroll
        for (int t = 0; t < 2; ++t) {
            int r = srow + t * 16;
            gl_lds16(A + (size_t)(m0 + r) * 1024 + k0 + scol, &At[(w * 2 + t) * 512]);
            gl_lds16(W + (size_t)(n0 + r) * 1024 + k0 + scol, &Bt[(w * 2 + t) * 512]);
        }
        __syncthreads();
        f16x8 af[4], bf[4];
#pragma unroll
        for (int mt = 0; mt < 4; ++mt) af[mt] = *(const f16x8*)&At[(wm + mt * 16 + c) * 32 + g * 8];
#pragma unroll
        for (int nt = 0; nt < 4; ++nt) bf[nt] = *(const f16x8*)&Bt[(wn + nt * 16 + c) * 32 + g * 8];
#pragma unroll
        for (int mt = 0; mt < 4; ++mt)
#pragma unroll
            for (int nt = 0; nt < 4; ++nt)
                acc[mt][nt] = MFMA16(af[mt], bf[nt], acc[mt][nt]);
    }

    if (z == 0) {
#pragma unroll
        for (int mt = 0; mt < 4; ++mt)
#pragma unroll
            for (int nt = 0; nt < 4; ++nt) {
                int col = n0 + wn + nt * 16 + c;
                int hh = col >> 6, dd = col & 63;
                int dc = dd >> 4, hi2 = (dd >> 3) & 1, j = dd & 7;
                float bb = bias[col];
                int row0 = m0 + wm + mt * 16 + g * 4;
                int bbi = row0 >> 10;
                int qtq = (row0 >> 5) & 31;
                int q50 = row0 & 31;
                size_t base = ((((size_t)(bbi * 16 + hh) * 32 + qtq) * 4 + dc) * 32) * 16 +
                              hi2 * 8 + j;
#pragma unroll
                for (int i = 0; i < 4; ++i)
                    qT[base + (size_t)(q50 + i) * 16] = (_Float16)(acc[mt][nt][i] + bb);
            }
    } else if (z == 1) {
#pragma unroll
        for (int mt = 0; mt < 4; ++mt)
#pragma unroll
            for (int nt = 0; nt < 4; ++nt) {
                int col = n0 + wn + nt * 16 + c;
                int hh = col >> 6, dd = col & 63;
                int dc = dd >> 4, hi2 = (dd >> 3) & 1, j = dd & 7;
                float bb = bias[col];
                int row0 = m0 + wm + mt * 16 + g * 4;
                int bbi = row0 >> 10, nn = row0 & 1023;
                int wa = nn >> 7, kt = (nn >> 5) & 3, q50 = nn & 31;
                size_t base = (((((size_t)(bbi * 16 + hh) * 8 + wa) * 4 + kt) * 4 + dc) * 32) * 16 +
                              hi2 * 8 + j;
#pragma unroll
                for (int i = 0; i < 4; ++i)
                    kT[base + (size_t)(q50 + i) * 16] = (_Float16)(acc[mt][nt][i] + bb);
            }
    } else {
#pragma unroll
        for (int mt = 0; mt < 4; ++mt)
#pragma unroll
            for (int nt = 0; nt < 4; ++nt) {
                int col = n0 + wn + nt * 16 + c;
                int hh = col >> 6, dd = col & 63;
                int dh = dd >> 5, q5v = dd & 31;
                float bb = bias[col];
                int row0 = m0 + wm + mt * 16 + g * 4;
                int bbi = row0 >> 10, nn = row0 & 1023;
                int wa = nn >> 7, kt = (nn >> 5) & 3;
                int ks = (nn >> 4) & 1, hi2 = (nn >> 3) & 1, j0 = nn & 7;
                f16x4 pk;
#pragma unroll
                for (int i = 0; i < 4; ++i) pk[i] = (_Float16)(acc[mt][nt][i] + bb);
                size_t off = ((((((size_t)(bbi * 16 + hh) * 8 + wa) * 4 + kt) * 2 + dh) * 2 + ks) * 32 +
                              q5v) * 16 + hi2 * 8 + j0;
                *(f16x4*)&vT[off] = pk;
            }
    }
}

// ---------------------------------------------------------------------------
// fused attention v9 = v8 + explicit cross-phase prefetch (v8 was
// latency-serialized: loads issued at use site, 2 waves/SIMD can't hide).
//  - K(p) kt0-1 + Q(p): prefetched during pair p-1 (loop-carried kpf/qpf).
//  - K(p) kt2-3 and V(p) kt0-1: issued at pair start (covered by O-reduce +
//    QK kt0-1 MFMAs; K/V are L2-hot ~250cy).
//  - V(p) kt2-3: issued right after barrier A (covered by fixup+pack).
//  - K(p+1) prefetch right after QK consumes kpf; Q(p+1) after PV.
// Register ledger peaks ~248 of the 256 cap (512thr, 2 waves/SIMD).
// ---------------------------------------------------------------------------
__global__ __launch_bounds__(512, 2) void attn(
    const _Float16* __restrict__ qT, const _Float16* __restrict__ kT,
    const _Float16* __restrict__ vT, float* __restrict__ O,
    _Float16* __restrict__ part0, _Float16* __restrict__ part1) {
    extern __shared__ __align__(16) char smem[];
    float* Obuf = (float*)smem;                 // [8][32][68] f32 = 69632
    float* red_m = (float*)(smem + 69632);      // [8][32]
    float* red_l = red_m + 256;                 // [8][32]

    const int tid = threadIdx.x, w = tid >> 6, lane = tid & 63;
    const int q5 = lane & 31, hi = lane >> 5;

    const int f = blockIdx.x;
    const int grp = f & 7, qt = f >> 3, q0 = qt * 32;
    const int chunk = grp & 1, b2 = grp >> 1;

    const int lofs = q5 * 16 + hi * 8;  // per-lane offset within a 1KB page

    // Bsel B-fragments: Bsel[ks](k,n) = (k == n&15 && n>>4 == ks)
    f16x8 bsel[2];
#pragma unroll
    for (int ks = 0; ks < 2; ++ks)
#pragma unroll
        for (int j = 0; j < 8; ++j)
            bsel[ks][j] = (hi * 8 + j == (q5 & 15) && (q5 >> 4) == ks)
                              ? (_Float16)1.0f : (_Float16)0.0f;

    f32x16 aacc[4] = {};

    // loop-carried prefetch buffers (next pair's K kt0-1 and Q)
    f16x8 kpf[2][4], qpf[4];
    {
        const int m = b2 * 16 + chunk * 8;
        const int head = (m & 3) * 16 + (m >> 2);
        const _Float16* kb = kT + ((size_t)head * 8 + w) * 8192 + lofs;
        const _Float16* qb = qT + ((size_t)head * 32 + qt) * 2048 + lofs;
#pragma unroll
        for (int kt = 0; kt < 2; ++kt)
#pragma unroll
            for (int dc = 0; dc < 4; ++dc)
                kpf[kt][dc] = *(const f16x8*)(kb + kt * 2048 + dc * 512);
#pragma unroll
        for (int dc = 0; dc < 4; ++dc) qpf[dc] = *(const f16x8*)(qb + dc * 512);
    }

#pragma unroll 1
    for (int p = 0; p < 8; ++p) {
        const int m = b2 * 16 + chunk * 8 + p;
        const int head = (m & 3) * 16 + (m >> 2);
        const _Float16* kb = kT + ((size_t)head * 8 + w) * 8192 + lofs;
        const _Float16* vb = vT + ((size_t)head * 8 + w) * 8192 + lofs;

        // ---- issue current-pair K kt2-3 + V kt0-1 (covered by reduce+QK) ----
        f16x8 kf2[4], kf3[4];
#pragma unroll
        for (int dc = 0; dc < 4; ++dc) {
            kf2[dc] = *(const f16x8*)(kb + 2 * 2048 + dc * 512);
            kf3[dc] = *(const f16x8*)(kb + 3 * 2048 + dc * 512);
        }
        f16x8 vf[4][2][2];
#pragma unroll
        for (int kt = 0; kt < 2; ++kt)
#pragma unroll
            for (int dh = 0; dh < 2; ++dh)
#pragma unroll
                for (int ks = 0; ks < 2; ++ks)
                    vf[kt][dh][ks] = *(const f16x8*)(vb + kt * 2048 + dh * 1024 + ks * 512);

        // ---- pipelined O-reduce of pair p-1 (LDS; overlaps load latency) ----
        if (p) {
            int mp = m - 1; int bp = mp & 3, hp = mp >> 2;
            int qq = tid >> 4, dd = (tid & 15) * 4;
            f32x4 acc = {};
#pragma unroll
            for (int buf = 0; buf < 8; ++buf) {
                f32x4 v = *(f32x4*)&Obuf[buf * 2176 + qq * 68 + dd];
                acc += v;
            }
            *(f32x4*)(O + (size_t)bp * 1048576 + (size_t)(q0 + qq) * 1024 + hp * 64 + dd) = acc;
        }

        // ---- QK^T: kt0-1 from prefetch (resident), kt2-3 from this body ----
        f32x16 s[4] = {};
#pragma unroll
        for (int dc = 0; dc < 4; ++dc) s[0] = MFMA32(kpf[0][dc], qpf[dc], s[0]);
#pragma unroll
        for (int dc = 0; dc < 4; ++dc) s[1] = MFMA32(kpf[1][dc], qpf[dc], s[1]);
#pragma unroll
        for (int dc = 0; dc < 4; ++dc) s[2] = MFMA32(kf2[dc], qpf[dc], s[2]);
#pragma unroll
        for (int dc = 0; dc < 4; ++dc) s[3] = MFMA32(kf3[dc], qpf[dc], s[3]);

        // ---- prefetch K(p+1) kt0-1 (covered by softmax+pack+PV) ----
        if (p < 7) {
            const int mn = m + 1;
            const int headn = (mn & 3) * 16 + (mn >> 2);
            const _Float16* kbn = kT + ((size_t)headn * 8 + w) * 8192 + lofs;
#pragma unroll
            for (int kt = 0; kt < 2; ++kt)
#pragma unroll
                for (int dc = 0; dc < 4; ++dc)
                    kpf[kt][dc] = *(const f16x8*)(kbn + kt * 2048 + dc * 512);
        }

        // ---- local (wave) max + exp + sum ----
        float pm = -3.0e38f;
#pragma unroll
        for (int kt = 0; kt < 4; ++kt)
#pragma unroll
            for (int r = 0; r < 16; ++r) pm = fmaxf(pm, s[kt][r]);
        pm = fmaxf(pm, __shfl_xor(pm, 32, 64));
        float l = 0.f;
#pragma unroll
        for (int kt = 0; kt < 4; ++kt)
#pragma unroll
            for (int r = 0; r < 16; ++r) {
                float e = exp2f((s[kt][r] - pm) * C1);
                s[kt][r] = e; l += e;
            }
        l += __shfl_xor(l, 32, 64);
        if (hi == 0) { red_m[w * 32 + q5] = pm; red_l[w * 32 + q5] = l; }
        __syncthreads();  // A

        // ---- issue V kt2-3 (covered by fixup+pack) ----
#pragma unroll
        for (int kt = 2; kt < 4; ++kt)
#pragma unroll
            for (int dh = 0; dh < 2; ++dh)
#pragma unroll
                for (int ks = 0; ks < 2; ++ks)
                    vf[kt][dh][ks] = *(const f16x8*)(vb + kt * 2048 + dh * 1024 + ks * 512);

        // ---- global fixup over 8 waves ----
        float mr[4], lr[4], M = -3.0e38f;
#pragma unroll
        for (int t = 0; t < 4; ++t) {
            int wv = hi * 4 + t;
            mr[t] = red_m[wv * 32 + q5];
            lr[t] = red_l[wv * 32 + q5];
            M = fmaxf(M, mr[t]);
        }
        M = fmaxf(M, __shfl_xor(M, 32, 64));
        float L = 0.f;
#pragma unroll
        for (int t = 0; t < 4; ++t) L += lr[t] * exp2f((mr[t] - M) * C1);
        L += __shfl_xor(L, 32, 64);
        const float sc = exp2f((pm - M) * C1) / L;

        // ---- pack P = e*sc -> f16 pairs, half-wave exchange -> av ----
        u32x4 av[4][2];
#pragma unroll
        for (int kt = 0; kt < 4; ++kt) {
            unsigned pw[8];
#pragma unroll
            for (int r2 = 0; r2 < 8; ++r2) {
                f16x2 t2;
                t2[0] = (_Float16)(s[kt][2 * r2] * sc);
                t2[1] = (_Float16)(s[kt][2 * r2 + 1] * sc);
                pw[r2] = __builtin_bit_cast(unsigned, t2);
            }
            unsigned recv[2][2];
#pragma unroll
            for (int ks = 0; ks < 2; ++ks)
#pragma unroll
                for (int d = 0; d < 2; ++d) {
                    unsigned send = hi ? pw[4 * ks + d] : pw[4 * ks + 2 + d];
                    recv[ks][d] = (unsigned)__shfl_xor((int)send, 32, 64);
                }
#pragma unroll
            for (int ks = 0; ks < 2; ++ks) {
                unsigned own0 = hi ? pw[4 * ks + 2] : pw[4 * ks + 0];
                unsigned own1 = hi ? pw[4 * ks + 3] : pw[4 * ks + 1];
                u32x4 a;
                a[0] = hi ? recv[ks][0] : own0;
                a[1] = hi ? recv[ks][1] : own1;
                a[2] = hi ? own0 : recv[ks][0];
                a[3] = hi ? own1 : recv[ks][1];
                av[kt][ks] = a;
            }
        }

        // ---- PV + MFMA-avg (V resident via early issue) ----
        f32x16 o0 = {}, o1 = {};
#pragma unroll
        for (int kt = 0; kt < 4; ++kt) {
#pragma unroll
            for (int ks = 0; ks < 2; ++ks) {
                f16x8 pa = __builtin_bit_cast(f16x8, av[kt][ks]);
                o0 = MFMA32(pa, vf[kt][0][ks], o0);
                o1 = MFMA32(pa, vf[kt][1][ks], o1);
            }
            aacc[kt] = MFMA32(__builtin_bit_cast(f16x8, av[kt][0]), bsel[0], aacc[kt]);
            aacc[kt] = MFMA32(__builtin_bit_cast(f16x8, av[kt][1]), bsel[1], aacc[kt]);
        }

        // ---- prefetch Q(p+1) (covered by Obuf write + barrier + reduce) ----
        if (p < 7) {
            const int mn = m + 1;
            const int headn = (mn & 3) * 16 + (mn >> 2);
            const _Float16* qbn = qT + ((size_t)headn * 32 + qt) * 2048 + lofs;
#pragma unroll
            for (int dc = 0; dc < 4; ++dc) qpf[dc] = *(const f16x8*)(qbn + dc * 512);
        }

        // ---- O partials to Obuf ----
        float* ob = Obuf + w * 2176;
#pragma unroll
        for (int r = 0; r < 16; ++r) {
            int qq = (r & 3) + 8 * (r >> 2) + 4 * hi;
            ob[qq * 68 + q5] = o0[r];
            ob[qq * 68 + 32 + q5] = o1[r];
        }
        __syncthreads();  // C
    }

    // ---- final reduce + store O for pair 7 ----
    {
        int mp = b2 * 16 + chunk * 8 + 7; int bp = mp & 3, hp = mp >> 2;
        int qq = tid >> 4, dd = (tid & 15) * 4;
        f32x4 acc = {};
#pragma unroll
        for (int buf = 0; buf < 8; ++buf) {
            f32x4 v = *(f32x4*)&Obuf[buf * 2176 + qq * 68 + dd];
            acc += v;
        }
        *(f32x4*)(O + (size_t)bp * 1048576 + (size_t)(q0 + qq) * 1024 + hp * 64 + dd) = acc;
    }

    // ---- A_avg tail: non-atomic f16 partial stores (one writer/element) ----
    {
        _Float16* pb = (chunk ? part1 : part0) + ((size_t)b2 * 1024 + q0) * 1024;
#pragma unroll
        for (int kt = 0; kt < 4; ++kt) {
            int k = w * 128 + kt * 32 + q5;
#pragma unroll
            for (int r = 0; r < 16; ++r) {
                int qq = (r & 3) + 8 * (r >> 2) + 4 * hi;
                pb[(size_t)qq * 1024 + k] = (_Float16)aacc[kt][r];
            }
        }
    }
}

// ---------------------------------------------------------------------------
// A_avg = (part0 + part1) / 16
// ---------------------------------------------------------------------------
__global__ void add_avg(const _Float16* __restrict__ p0,
                        const _Float16* __restrict__ p1,
                        float* __restrict__ out) {
    int i = blockIdx.x * blockDim.x + threadIdx.x;  // groups of 8
    f16x8 a = ((const f16x8*)p0)[i];
    f16x8 b = ((const f16x8*)p1)[i];
    f32x4 r0, r1;
#pragma unroll
    for (int j = 0; j < 4; ++j) r0[j] = ((float)a[j] + (float)b[j]) * 0.0625f;
#pragma unroll
    for (int j = 0; j < 4; ++j) r1[j] = ((float)a[4 + j] + (float)b[4 + j]) * 0.0625f;
    *(f32x4*)&out[8 * i] = r0;
    *(f32x4*)&out[8 * i + 4] = r1;
}

// ---------------------------------------------------------------------------
extern "C" void kernel_launch(void* const* d_in, const int* in_sizes, int n_in,
                              void* d_out, int out_size, void* d_ws, size_t ws_size,
                              hipStream_t stream) {
    if (ws_size < ((size_t)46 << 20)) return;  // need 46 MB scratch

    const float* Q  = (const float*)d_in[0];
    const float* K  = (const float*)d_in[1];
    const float* Wq = (const float*)d_in[2];
    const float* bq = (const float*)d_in[3];
    const float* Wk = (const float*)d_in[4];
    const float* bk = (const float*)d_in[5];
    const float* Wv = (const float*)d_in[6];
    const float* bv = (const float*)d_in[7];

    char* ws = (char*)d_ws;
    _Float16* Qh  = (_Float16*)(ws);                      //  8 MB
    _Float16* Kh  = (_Float16*)(ws + ((size_t)8 << 20));  //  8 MB
    _Float16* Wqh = (_Float16*)(ws + ((size_t)16 << 20)); //  2 MB
    _Float16* Wkh = (_Float16*)(ws + ((size_t)18 << 20)); //  2 MB
    _Float16* Wvh = (_Float16*)(ws + ((size_t)20 << 20)); //  2 MB
    _Float16* qT  = (_Float16*)(ws + ((size_t)22 << 20)); //  8 MB (tiled)
    _Float16* kT  = (_Float16*)(ws + ((size_t)30 << 20)); //  8 MB (tiled)
    _Float16* vT  = (_Float16*)(ws + ((size_t)38 << 20)); //  8 MB (tiled)
    // partials alias Qh/Kh (dead after proj_gemm)
    _Float16* part0 = (_Float16*)(ws);                     // 8 MB
    _Float16* part1 = (_Float16*)(ws + ((size_t)8 << 20)); // 8 MB

    float* O = (float*)d_out;
    float* Aavg = O + (size_t)4 * 1024 * 1024;

    // 1) convert inputs to fp16
    cvt_all<<<dim3(1441792 / 256), 256, 0, stream>>>(Q, K, Wq, Wk, Wv, Qh);

    // 2) three projection GEMMs (tiled outputs)
    proj_gemm<<<dim3(32, 8, 3), 256, 0, stream>>>(Qh, Kh, Wqh, Wkh, Wvh,
                                                  bq, bk, bv, qT, kT, vT);

    // 3) fused attention: 256 blocks x 512 threads, 71680 B LDS
    const int SMEM = 71680;
    hipFuncSetAttribute((const void*)attn, hipFuncAttributeMaxDynamicSharedMemorySize, SMEM);
    attn<<<dim3(256), 512, SMEM, stream>>>(qT, kT, vT, O, part0, part1);

    // 4) A_avg = (part0 + part1) / 16
    add_avg<<<dim3(2048), 256, 0, stream>>>(part0, part1, Aavg);
}

// Round 10
// 127.306 us; speedup vs baseline: 1.1655x; 1.1655x over previous
//
#include <hip/hip_runtime.h>
#include <hip/hip_bf16.h>
#include <hip/hip_fp16.h>

typedef _Float16 f16x8 __attribute__((ext_vector_type(8)));
typedef _Float16 f16x4 __attribute__((ext_vector_type(4)));
typedef _Float16 f16x2 __attribute__((ext_vector_type(2)));
typedef float f32x4 __attribute__((ext_vector_type(4)));
typedef float f32x16 __attribute__((ext_vector_type(16)));
typedef unsigned int u32x4 __attribute__((ext_vector_type(4)));

#define MFMA16(a, b, c) __builtin_amdgcn_mfma_f32_16x16x32_f16(a, b, c, 0, 0, 0)
#define MFMA32(a, b, c) __builtin_amdgcn_mfma_f32_32x32x16_f16(a, b, c, 0, 0, 0)

// log2(e) / sqrt(1024)
#define C1 0.045084220027780106f

#define LGKM0_BARRIER do { \
    asm volatile("s_waitcnt lgkmcnt(0)" ::: "memory"); \
    __builtin_amdgcn_s_barrier(); \
} while (0)

// ---------------------------------------------------------------------------
// convert f32 -> fp16 for Q, K, Wq, Wk, Wv into one contiguous ws region
// ---------------------------------------------------------------------------
__global__ void cvt_all(const float* __restrict__ Q, const float* __restrict__ K,
                        const float* __restrict__ Wq, const float* __restrict__ Wk,
                        const float* __restrict__ Wv, _Float16* __restrict__ dst) {
    int i = blockIdx.x * blockDim.x + threadIdx.x;  // i indexes groups of 8 f32
    const float* s;
    int off;
    if (i < 524288)       { s = Q;  off = 0;       }
    else if (i < 1048576) { s = K;  off = 524288;  }
    else if (i < 1179648) { s = Wq; off = 1048576; }
    else if (i < 1310720) { s = Wk; off = 1179648; }
    else                  { s = Wv; off = 1310720; }
    int j = i - off;
    float4 a = ((const float4*)s)[2 * j];
    float4 b = ((const float4*)s)[2 * j + 1];
    f16x8 h;
    h[0] = (_Float16)a.x; h[1] = (_Float16)a.y; h[2] = (_Float16)a.z; h[3] = (_Float16)a.w;
    h[4] = (_Float16)b.x; h[5] = (_Float16)b.y; h[6] = (_Float16)b.z; h[7] = (_Float16)b.w;
    ((f16x8*)dst)[i] = h;
}

// ---------------------------------------------------------------------------
// projection GEMM: C[m,n] = A[m,:]·W[n,:] + bias[n]
// Outputs in attention-fragment-tiled layouts (1KB coalesced pages):
//  qT[head][qt 32][dc 4][q5 32][hi 2][j 8]
//  kT[head][w 8][kt 4][dc 4][q5 32][hi 2][j 8]
//  vT[head][w 8][kt 4][dh 2][ks 2][q5 32][hi 2][j 8]
// ---------------------------------------------------------------------------
__device__ __forceinline__ void gl_lds16(const void* g, void* l) {
    __builtin_amdgcn_global_load_lds(
        (const __attribute__((address_space(1))) void*)g,
        (__attribute__((address_space(3))) void*)l, 16, 0, 0);
}

__global__ __launch_bounds__(256) void proj_gemm(
    const _Float16* __restrict__ Qh, const _Float16* __restrict__ Kh,
    const _Float16* __restrict__ Wqh, const _Float16* __restrict__ Wkh,
    const _Float16* __restrict__ Wvh,
    const float* __restrict__ bq, const float* __restrict__ bk,
    const float* __restrict__ bv,
    _Float16* __restrict__ qT, _Float16* __restrict__ kT,
    _Float16* __restrict__ vT) {
    const int z = blockIdx.z;
    const _Float16* A = (z == 0) ? Qh : Kh;
    const _Float16* W = (z == 0) ? Wqh : (z == 1 ? Wkh : Wvh);
    const float* bias = (z == 0) ? bq : (z == 1 ? bk : bv);

    __shared__ __align__(16) _Float16 At[128 * 32];
    __shared__ __align__(16) _Float16 Bt[128 * 32];

    const int tid = threadIdx.x;
    const int w = tid >> 6, lane = tid & 63;
    const int g = lane >> 4, c = lane & 15;
    const int m0 = blockIdx.x * 128, n0 = blockIdx.y * 128;
    const int wm = (w & 1) * 64, wn = (w >> 1) * 64;
    const int srow = w * 32 + (lane >> 2);
    const int scol = (lane & 3) * 8;  // in halves

    f32x4 acc[4][4] = {};

    for (int k0 = 0; k0 < 1024; k0 += 32) {
        __syncthreads();
#pragma unroll
        for (int t = 0; t < 2; ++t) {
            int r = srow + t * 16;
            gl_lds16(A + (size_t)(m0 + r) * 1024 + k0 + scol, &At[(w * 2 + t) * 512]);
            gl_lds16(W + (size_t)(n0 + r) * 1024 + k0 + scol, &Bt[(w * 2 + t) * 512]);
        }
        __syncthreads();
        f16x8 af[4], bf[4];
#pragma unroll
        for (int mt = 0; mt < 4; ++mt) af[mt] = *(const f16x8*)&At[(wm + mt * 16 + c) * 32 + g * 8];
#pragma unroll
        for (int nt = 0; nt < 4; ++nt) bf[nt] = *(const f16x8*)&Bt[(wn + nt * 16 + c) * 32 + g * 8];
#pragma unroll
        for (int mt = 0; mt < 4; ++mt)
#pragma unroll
            for (int nt = 0; nt < 4; ++nt)
                acc[mt][nt] = MFMA16(af[mt], bf[nt], acc[mt][nt]);
    }

    if (z == 0) {
#pragma unroll
        for (int mt = 0; mt < 4; ++mt)
#pragma unroll
            for (int nt = 0; nt < 4; ++nt) {
                int col = n0 + wn + nt * 16 + c;
                int hh = col >> 6, dd = col & 63;
                int dc = dd >> 4, hi2 = (dd >> 3) & 1, j = dd & 7;
                float bb = bias[col];
                int row0 = m0 + wm + mt * 16 + g * 4;
                int bbi = row0 >> 10;
                int qtq = (row0 >> 5) & 31;
                int q50 = row0 & 31;
                size_t base = ((((size_t)(bbi * 16 + hh) * 32 + qtq) * 4 + dc) * 32) * 16 +
                              hi2 * 8 + j;
#pragma unroll
                for (int i = 0; i < 4; ++i)
                    qT[base + (size_t)(q50 + i) * 16] = (_Float16)(acc[mt][nt][i] + bb);
            }
    } else if (z == 1) {
#pragma unroll
        for (int mt = 0; mt < 4; ++mt)
#pragma unroll
            for (int nt = 0; nt < 4; ++nt) {
                int col = n0 + wn + nt * 16 + c;
                int hh = col >> 6, dd = col & 63;
                int dc = dd >> 4, hi2 = (dd >> 3) & 1, j = dd & 7;
                float bb = bias[col];
                int row0 = m0 + wm + mt * 16 + g * 4;
                int bbi = row0 >> 10, nn = row0 & 1023;
                int wa = nn >> 7, kt = (nn >> 5) & 3, q50 = nn & 31;
                size_t base = (((((size_t)(bbi * 16 + hh) * 8 + wa) * 4 + kt) * 4 + dc) * 32) * 16 +
                              hi2 * 8 + j;
#pragma unroll
                for (int i = 0; i < 4; ++i)
                    kT[base + (size_t)(q50 + i) * 16] = (_Float16)(acc[mt][nt][i] + bb);
            }
    } else {
#pragma unroll
        for (int mt = 0; mt < 4; ++mt)
#pragma unroll
            for (int nt = 0; nt < 4; ++nt) {
                int col = n0 + wn + nt * 16 + c;
                int hh = col >> 6, dd = col & 63;
                int dh = dd >> 5, q5v = dd & 31;
                float bb = bias[col];
                int row0 = m0 + wm + mt * 16 + g * 4;
                int bbi = row0 >> 10, nn = row0 & 1023;
                int wa = nn >> 7, kt = (nn >> 5) & 3;
                int ks = (nn >> 4) & 1, hi2 = (nn >> 3) & 1, j0 = nn & 7;
                f16x4 pk;
#pragma unroll
                for (int i = 0; i < 4; ++i) pk[i] = (_Float16)(acc[mt][nt][i] + bb);
                size_t off = ((((((size_t)(bbi * 16 + hh) * 8 + wa) * 4 + kt) * 2 + dh) * 2 + ks) * 32 +
                              q5v) * 16 + hi2 * 8 + j0;
                *(f16x4*)&vT[off] = pk;
            }
    }
}

// ---------------------------------------------------------------------------
// fused attention v10: 512 threads (8 waves), direct tiled global loads with
// a REGISTER-BUDGETED rotating pipeline (v9 spilled: full-pair prefetch needed
// ~320 regs; this uses 4x16-reg rotating buffers, peak ~232 of the 256 cap).
//  - early pack: e->f16 av right after exp (s[4]=64 regs dies); after fixup
//    av *= sc via v_pk_mul_f16 (sc is lane-uniform in A-layout).
//  - issue schedule (each load >=400cy ahead of use): K2/K3 during QK0/1,
//    V1 during QK2, V2/V3 during softmax, K0'/K1'/V0'/Q' during PV.
//  - raw s_barrier + producer lgkmcnt(0): no vmcnt drain at barriers, loads
//    stay in flight across them.
// ---------------------------------------------------------------------------
__global__ __launch_bounds__(512, 2) void attn(
    const _Float16* __restrict__ qT, const _Float16* __restrict__ kT,
    const _Float16* __restrict__ vT, float* __restrict__ O,
    _Float16* __restrict__ part0, _Float16* __restrict__ part1) {
    extern __shared__ __align__(16) char smem[];
    float* Obuf = (float*)smem;                 // [8][32][68] f32 = 69632
    float* red_m = (float*)(smem + 69632);      // [8][32]
    float* red_l = red_m + 256;                 // [8][32]

    const int tid = threadIdx.x, w = tid >> 6, lane = tid & 63;
    const int q5 = lane & 31, hi = lane >> 5;

    const int f = blockIdx.x;
    const int grp = f & 7, qt = f >> 3, q0 = qt * 32;
    const int chunk = grp & 1, b2 = grp >> 1;

    const int lofs = q5 * 16 + hi * 8;  // per-lane offset within a 1KB page

    // Bsel B-fragments: Bsel[ks](k,n) = (k == n&15 && n>>4 == ks)
    f16x8 bsel[2];
#pragma unroll
    for (int ks = 0; ks < 2; ++ks)
#pragma unroll
        for (int j = 0; j < 8; ++j)
            bsel[ks][j] = (hi * 8 + j == (q5 & 15) && (q5 >> 4) == ks)
                              ? (_Float16)1.0f : (_Float16)0.0f;

    f32x16 aacc[4] = {};

    // rotating buffers (16 regs each)
    f16x8 bK0[4], bK1[4], bV0[4], bV1[4], qf[4];

    // ---- prologue: issue K0,K1,V0,Q of pair 0 ----
    {
        const int m0p = b2 * 16 + chunk * 8;
        const int head = (m0p & 3) * 16 + (m0p >> 2);
        const _Float16* kb = kT + ((size_t)head * 8 + w) * 8192 + lofs;
        const _Float16* vb = vT + ((size_t)head * 8 + w) * 8192 + lofs;
        const _Float16* qb = qT + ((size_t)head * 32 + qt) * 2048 + lofs;
#pragma unroll
        for (int dc = 0; dc < 4; ++dc) bK0[dc] = *(const f16x8*)(kb + dc * 512);
#pragma unroll
        for (int dc = 0; dc < 4; ++dc) bK1[dc] = *(const f16x8*)(kb + 2048 + dc * 512);
#pragma unroll
        for (int i = 0; i < 4; ++i) bV0[i] = *(const f16x8*)(vb + i * 512);
#pragma unroll
        for (int dc = 0; dc < 4; ++dc) qf[dc] = *(const f16x8*)(qb + dc * 512);
    }

#pragma unroll 1
    for (int p = 0; p < 8; ++p) {
        const int m = b2 * 16 + chunk * 8 + p;
        const int head = (m & 3) * 16 + (m >> 2);
        const _Float16* kb = kT + ((size_t)head * 8 + w) * 8192 + lofs;
        const _Float16* vb = vT + ((size_t)head * 8 + w) * 8192 + lofs;
        const int mn = m + 1;
        const int headn = (mn & 3) * 16 + (mn >> 2);
        const _Float16* kbn = kT + ((size_t)headn * 8 + w) * 8192 + lofs;
        const _Float16* vbn = vT + ((size_t)headn * 8 + w) * 8192 + lofs;
        const _Float16* qbn = qT + ((size_t)headn * 32 + qt) * 2048 + lofs;

        // ---- pipelined O-reduce of pair p-1 (Obuf synced by barrier C) ----
        if (p) {
            int mp = m - 1; int bp = mp & 3, hp = mp >> 2;
            int qq = tid >> 4, dd = (tid & 15) * 4;
            f32x4 acc = {};
#pragma unroll
            for (int buf = 0; buf < 8; ++buf) {
                f32x4 v = *(f32x4*)&Obuf[buf * 2176 + qq * 68 + dd];
                acc += v;
            }
            *(f32x4*)(O + (size_t)bp * 1048576 + (size_t)(q0 + qq) * 1024 + hp * 64 + dd) = acc;
        }

        // ---- QK^T with rotating K buffers ----
        f32x16 s0 = {}, s1 = {}, s2 = {}, s3 = {};
#pragma unroll
        for (int dc = 0; dc < 4; ++dc) s0 = MFMA32(bK0[dc], qf[dc], s0);
#pragma unroll
        for (int dc = 0; dc < 4; ++dc) bK0[dc] = *(const f16x8*)(kb + 2 * 2048 + dc * 512);  // K2
#pragma unroll
        for (int dc = 0; dc < 4; ++dc) s1 = MFMA32(bK1[dc], qf[dc], s1);
#pragma unroll
        for (int dc = 0; dc < 4; ++dc) bK1[dc] = *(const f16x8*)(kb + 3 * 2048 + dc * 512);  // K3
#pragma unroll
        for (int dc = 0; dc < 4; ++dc) s2 = MFMA32(bK0[dc], qf[dc], s2);
#pragma unroll
        for (int i = 0; i < 4; ++i) bV1[i] = *(const f16x8*)(vb + 1 * 2048 + i * 512);       // V1
#pragma unroll
        for (int dc = 0; dc < 4; ++dc) s3 = MFMA32(bK1[dc], qf[dc], s3);

        // ---- local (wave) max + exp + sum ----
        float pm = -3.0e38f;
#pragma unroll
        for (int r = 0; r < 16; ++r) {
            pm = fmaxf(pm, s0[r]); pm = fmaxf(pm, s1[r]);
            pm = fmaxf(pm, s2[r]); pm = fmaxf(pm, s3[r]);
        }
        pm = fmaxf(pm, __shfl_xor(pm, 32, 64));
        float l = 0.f;
#pragma unroll
        for (int r = 0; r < 16; ++r) {
            float e0 = exp2f((s0[r] - pm) * C1); s0[r] = e0;
            float e1 = exp2f((s1[r] - pm) * C1); s1[r] = e1;
            float e2 = exp2f((s2[r] - pm) * C1); s2[r] = e2;
            float e3 = exp2f((s3[r] - pm) * C1); s3[r] = e3;
            l += (e0 + e1) + (e2 + e3);
        }
        l += __shfl_xor(l, 32, 64);
        if (hi == 0) { red_m[w * 32 + q5] = pm; red_l[w * 32 + q5] = l; }

        // ---- early pack: e -> f16 av (s dies here) ----
        u32x4 av[4][2];
#define PACK_KT(SK, KT) { \
            unsigned pw[8]; \
            _Pragma("unroll") \
            for (int r2 = 0; r2 < 8; ++r2) { \
                f16x2 t2; \
                t2[0] = (_Float16)SK[2 * r2]; \
                t2[1] = (_Float16)SK[2 * r2 + 1]; \
                pw[r2] = __builtin_bit_cast(unsigned, t2); \
            } \
            unsigned recv[2][2]; \
            _Pragma("unroll") \
            for (int ks = 0; ks < 2; ++ks) \
                _Pragma("unroll") \
                for (int d = 0; d < 2; ++d) { \
                    unsigned send = hi ? pw[4 * ks + d] : pw[4 * ks + 2 + d]; \
                    recv[ks][d] = (unsigned)__shfl_xor((int)send, 32, 64); \
                } \
            _Pragma("unroll") \
            for (int ks = 0; ks < 2; ++ks) { \
                unsigned own0 = hi ? pw[4 * ks + 2] : pw[4 * ks + 0]; \
                unsigned own1 = hi ? pw[4 * ks + 3] : pw[4 * ks + 1]; \
                u32x4 a; \
                a[0] = hi ? recv[ks][0] : own0; \
                a[1] = hi ? recv[ks][1] : own1; \
                a[2] = hi ? own0 : recv[ks][0]; \
                a[3] = hi ? own1 : recv[ks][1]; \
                av[KT][ks] = a; \
            } \
        }
        PACK_KT(s0, 0)
        PACK_KT(s1, 1)
        PACK_KT(s2, 2)
        PACK_KT(s3, 3)
#undef PACK_KT

        // ---- issue V2,V3 into the dead K buffers (covered by barrier+fixup) ----
#pragma unroll
        for (int i = 0; i < 4; ++i) bK0[i] = *(const f16x8*)(vb + 2 * 2048 + i * 512);  // V2
#pragma unroll
        for (int i = 0; i < 4; ++i) bK1[i] = *(const f16x8*)(vb + 3 * 2048 + i * 512);  // V3

        LGKM0_BARRIER;  // A (red_m/red_l produced; loads stay in flight)

        // ---- global fixup over 8 waves ----
        float mr[4], lr[4], M = -3.0e38f;
#pragma unroll
        for (int t = 0; t < 4; ++t) {
            int wv = hi * 4 + t;
            mr[t] = red_m[wv * 32 + q5];
            lr[t] = red_l[wv * 32 + q5];
            M = fmaxf(M, mr[t]);
        }
        M = fmaxf(M, __shfl_xor(M, 32, 64));
        float L = 0.f;
#pragma unroll
        for (int t = 0; t < 4; ++t) L += lr[t] * exp2f((mr[t] - M) * C1);
        L += __shfl_xor(L, 32, 64);
        const float sc = exp2f((pm - M) * C1) / L;

        // ---- scale av in place: P = e * sc (v_pk_mul_f16) ----
        {
            const _Float16 sch = (_Float16)sc;
            f16x8 scv;
#pragma unroll
            for (int j2 = 0; j2 < 8; ++j2) scv[j2] = sch;
#pragma unroll
            for (int kt = 0; kt < 4; ++kt)
#pragma unroll
                for (int ks = 0; ks < 2; ++ks)
                    av[kt][ks] = __builtin_bit_cast(
                        u32x4, __builtin_bit_cast(f16x8, av[kt][ks]) * scv);
        }

        // ---- PV + MFMA-avg with rotating V buffers + next-pair prefetch ----
        f32x16 o0 = {}, o1 = {};
        // kt0: bV0
#pragma unroll
        for (int ks = 0; ks < 2; ++ks) {
            f16x8 pa = __builtin_bit_cast(f16x8, av[0][ks]);
            o0 = MFMA32(pa, bV0[ks], o0);
            o1 = MFMA32(pa, bV0[2 + ks], o1);
        }
        aacc[0] = MFMA32(__builtin_bit_cast(f16x8, av[0][0]), bsel[0], aacc[0]);
        aacc[0] = MFMA32(__builtin_bit_cast(f16x8, av[0][1]), bsel[1], aacc[0]);
        // kt1: bV1
#pragma unroll
        for (int ks = 0; ks < 2; ++ks) {
            f16x8 pa = __builtin_bit_cast(f16x8, av[1][ks]);
            o0 = MFMA32(pa, bV1[ks], o0);
            o1 = MFMA32(pa, bV1[2 + ks], o1);
        }
        aacc[1] = MFMA32(__builtin_bit_cast(f16x8, av[1][0]), bsel[0], aacc[1]);
        aacc[1] = MFMA32(__builtin_bit_cast(f16x8, av[1][1]), bsel[1], aacc[1]);
        // kt2: bK0 (=V2); afterwards prefetch K0'(p+1) into bK0
#pragma unroll
        for (int ks = 0; ks < 2; ++ks) {
            f16x8 pa = __builtin_bit_cast(f16x8, av[2][ks]);
            o0 = MFMA32(pa, bK0[ks], o0);
            o1 = MFMA32(pa, bK0[2 + ks], o1);
        }
        aacc[2] = MFMA32(__builtin_bit_cast(f16x8, av[2][0]), bsel[0], aacc[2]);
        aacc[2] = MFMA32(__builtin_bit_cast(f16x8, av[2][1]), bsel[1], aacc[2]);
        if (p < 7) {
#pragma unroll
            for (int dc = 0; dc < 4; ++dc) bK0[dc] = *(const f16x8*)(kbn + dc * 512);      // K0'
#pragma unroll
            for (int i = 0; i < 4; ++i) bV0[i] = *(const f16x8*)(vbn + i * 512);           // V0'
        }
        // kt3: bK1 (=V3); afterwards prefetch K1'(p+1) + Q'
#pragma unroll
        for (int ks = 0; ks < 2; ++ks) {
            f16x8 pa = __builtin_bit_cast(f16x8, av[3][ks]);
            o0 = MFMA32(pa, bK1[ks], o0);
            o1 = MFMA32(pa, bK1[2 + ks], o1);
        }
        aacc[3] = MFMA32(__builtin_bit_cast(f16x8, av[3][0]), bsel[0], aacc[3]);
        aacc[3] = MFMA32(__builtin_bit_cast(f16x8, av[3][1]), bsel[1], aacc[3]);
        if (p < 7) {
#pragma unroll
            for (int dc = 0; dc < 4; ++dc) bK1[dc] = *(const f16x8*)(kbn + 2048 + dc * 512);  // K1'
#pragma unroll
            for (int dc = 0; dc < 4; ++dc) qf[dc] = *(const f16x8*)(qbn + dc * 512);          // Q'
        }

        // ---- O partials to Obuf ----
        float* ob = Obuf + w * 2176;
#pragma unroll
        for (int r = 0; r < 16; ++r) {
            int qq = (r & 3) + 8 * (r >> 2) + 4 * hi;
            ob[qq * 68 + q5] = o0[r];
            ob[qq * 68 + 32 + q5] = o1[r];
        }
        LGKM0_BARRIER;  // C (Obuf produced; prefetches stay in flight)
    }

    // ---- final reduce + store O for pair 7 ----
    {
        int mp = b2 * 16 + chunk * 8 + 7; int bp = mp & 3, hp = mp >> 2;
        int qq = tid >> 4, dd = (tid & 15) * 4;
        f32x4 acc = {};
#pragma unroll
        for (int buf = 0; buf < 8; ++buf) {
            f32x4 v = *(f32x4*)&Obuf[buf * 2176 + qq * 68 + dd];
            acc += v;
        }
        *(f32x4*)(O + (size_t)bp * 1048576 + (size_t)(q0 + qq) * 1024 + hp * 64 + dd) = acc;
    }

    // ---- A_avg tail: non-atomic f16 partial stores (one writer/element) ----
    {
        _Float16* pb = (chunk ? part1 : part0) + ((size_t)b2 * 1024 + q0) * 1024;
#pragma unroll
        for (int kt = 0; kt < 4; ++kt) {
            int k = w * 128 + kt * 32 + q5;
#pragma unroll
            for (int r = 0; r < 16; ++r) {
                int qq = (r & 3) + 8 * (r >> 2) + 4 * hi;
                pb[(size_t)qq * 1024 + k] = (_Float16)aacc[kt][r];
            }
        }
    }
}

// ---------------------------------------------------------------------------
// A_avg = (part0 + part1) / 16
// ---------------------------------------------------------------------------
__global__ void add_avg(const _Float16* __restrict__ p0,
                        const _Float16* __restrict__ p1,
                        float* __restrict__ out) {
    int i = blockIdx.x * blockDim.x + threadIdx.x;  // groups of 8
    f16x8 a = ((const f16x8*)p0)[i];
    f16x8 b = ((const f16x8*)p1)[i];
    f32x4 r0, r1;
#pragma unroll
    for (int j = 0; j < 4; ++j) r0[j] = ((float)a[j] + (float)b[j]) * 0.0625f;
#pragma unroll
    for (int j = 0; j < 4; ++j) r1[j] = ((float)a[4 + j] + (float)b[4 + j]) * 0.0625f;
    *(f32x4*)&out[8 * i] = r0;
    *(f32x4*)&out[8 * i + 4] = r1;
}

// ---------------------------------------------------------------------------
extern "C" void kernel_launch(void* const* d_in, const int* in_sizes, int n_in,
                              void* d_out, int out_size, void* d_ws, size_t ws_size,
                              hipStream_t stream) {
    if (ws_size < ((size_t)46 << 20)) return;  // need 46 MB scratch

    const float* Q  = (const float*)d_in[0];
    const float* K  = (const float*)d_in[1];
    const float* Wq = (const float*)d_in[2];
    const float* bq = (const float*)d_in[3];
    const float* Wk = (const float*)d_in[4];
    const float* bk = (const float*)d_in[5];
    const float* Wv = (const float*)d_in[6];
    const float* bv = (const float*)d_in[7];

    char* ws = (char*)d_ws;
    _Float16* Qh  = (_Float16*)(ws);                      //  8 MB
    _Float16* Kh  = (_Float16*)(ws + ((size_t)8 << 20));  //  8 MB
    _Float16* Wqh = (_Float16*)(ws + ((size_t)16 << 20)); //  2 MB
    _Float16* Wkh = (_Float16*)(ws + ((size_t)18 << 20)); //  2 MB
    _Float16* Wvh = (_Float16*)(ws + ((size_t)20 << 20)); //  2 MB
    _Float16* qT  = (_Float16*)(ws + ((size_t)22 << 20)); //  8 MB (tiled)
    _Float16* kT  = (_Float16*)(ws + ((size_t)30 << 20)); //  8 MB (tiled)
    _Float16* vT  = (_Float16*)(ws + ((size_t)38 << 20)); //  8 MB (tiled)
    // partials alias Qh/Kh (dead after proj_gemm)
    _Float16* part0 = (_Float16*)(ws);                     // 8 MB
    _Float16* part1 = (_Float16*)(ws + ((size_t)8 << 20)); // 8 MB

    float* O = (float*)d_out;
    float* Aavg = O + (size_t)4 * 1024 * 1024;

    // 1) convert inputs to fp16
    cvt_all<<<dim3(1441792 / 256), 256, 0, stream>>>(Q, K, Wq, Wk, Wv, Qh);

    // 2) three projection GEMMs (tiled outputs)
    proj_gemm<<<dim3(32, 8, 3), 256, 0, stream>>>(Qh, Kh, Wqh, Wkh, Wvh,
                                                  bq, bk, bv, qT, kT, vT);

    // 3) fused attention: 256 blocks x 512 threads, 71680 B LDS
    const int SMEM = 71680;
    hipFuncSetAttribute((const void*)attn, hipFuncAttributeMaxDynamicSharedMemorySize, SMEM);
    attn<<<dim3(256), 512, SMEM, stream>>>(qT, kT, vT, O, part0, part1);

    // 4) A_avg = (part0 + part1) / 16
    add_avg<<<dim3(2048), 256, 0, stream>>>(part0, part1, Aavg);
}

// Round 12
// 105.413 us; speedup vs baseline: 1.4076x; 1.2077x over previous
//
#include <hip/hip_runtime.h>
#include <hip/hip_bf16.h>
#include <hip/hip_fp16.h>

typedef _Float16 f16x8 __attribute__((ext_vector_type(8)));
typedef _Float16 f16x4 __attribute__((ext_vector_type(4)));
typedef _Float16 f16x2 __attribute__((ext_vector_type(2)));
typedef float f32x4 __attribute__((ext_vector_type(4)));
typedef float f32x16 __attribute__((ext_vector_type(16)));
typedef unsigned int u32x4 __attribute__((ext_vector_type(4)));

#define MFMA16(a, b, c) __builtin_amdgcn_mfma_f32_16x16x32_f16(a, b, c, 0, 0, 0)
#define MFMA32(a, b, c) __builtin_amdgcn_mfma_f32_32x32x16_f16(a, b, c, 0, 0, 0)

// log2(e) / sqrt(1024) — folded into qT at projection time
#define C1 0.045084220027780106f

#define LGKM0_BARRIER do { \
    asm volatile("s_waitcnt lgkmcnt(0)" ::: "memory"); \
    __builtin_amdgcn_s_barrier(); \
} while (0)

// ---------------------------------------------------------------------------
// convert f32 -> fp16 for Q, K, Wq, Wk, Wv into one contiguous ws region
// ---------------------------------------------------------------------------
__global__ void cvt_all(const float* __restrict__ Q, const float* __restrict__ K,
                        const float* __restrict__ Wq, const float* __restrict__ Wk,
                        const float* __restrict__ Wv, _Float16* __restrict__ dst) {
    int i = blockIdx.x * blockDim.x + threadIdx.x;  // i indexes groups of 8 f32
    const float* s;
    int off;
    if (i < 524288)       { s = Q;  off = 0;       }
    else if (i < 1048576) { s = K;  off = 524288;  }
    else if (i < 1179648) { s = Wq; off = 1048576; }
    else if (i < 1310720) { s = Wk; off = 1179648; }
    else                  { s = Wv; off = 1310720; }
    int j = i - off;
    float4 a = ((const float4*)s)[2 * j];
    float4 b = ((const float4*)s)[2 * j + 1];
    f16x8 h;
    h[0] = (_Float16)a.x; h[1] = (_Float16)a.y; h[2] = (_Float16)a.z; h[3] = (_Float16)a.w;
    h[4] = (_Float16)b.x; h[5] = (_Float16)b.y; h[6] = (_Float16)b.z; h[7] = (_Float16)b.w;
    ((f16x8*)dst)[i] = h;
}

// ---------------------------------------------------------------------------
// projection GEMM: C[m,n] = A[m,:]·W[n,:] + bias[n]
// Tiled outputs (1KB coalesced fragment pages):
//  qT[head][qt 32][dc 4][q5 32][hi 2][j 8]     (PRE-SCALED by C1)
//  kT[head][w 8][kt 4][dc 4][q5 32][hi 2][j 8]
//  vT[head][w 8][kt 4][dh 2][ks 2][q5 32][hi 2][j 8]
// q/k epilogue: LDS-transpose per mt step -> vectorized f16x8 stores
// (round-8..10 used 64 scalar 2B stores/thread — uncoalesced).
// ---------------------------------------------------------------------------
__device__ __forceinline__ void gl_lds16(const void* g, void* l) {
    __builtin_amdgcn_global_load_lds(
        (const __attribute__((address_space(1))) void*)g,
        (__attribute__((address_space(3))) void*)l, 16, 0, 0);
}

__global__ __launch_bounds__(256) void proj_gemm(
    const _Float16* __restrict__ Qh, const _Float16* __restrict__ Kh,
    const _Float16* __restrict__ Wqh, const _Float16* __restrict__ Wkh,
    const _Float16* __restrict__ Wvh,
    const float* __restrict__ bq, const float* __restrict__ bk,
    const float* __restrict__ bv,
    _Float16* __restrict__ qT, _Float16* __restrict__ kT,
    _Float16* __restrict__ vT) {
    const int z = blockIdx.z;
    const _Float16* A = (z == 0) ? Qh : Kh;
    const _Float16* W = (z == 0) ? Wqh : (z == 1 ? Wkh : Wvh);
    const float* bias = (z == 0) ? bq : (z == 1 ? bk : bv);

    __shared__ __align__(16) _Float16 At[128 * 32];
    __shared__ __align__(16) _Float16 Bt[128 * 32];
    __shared__ __align__(16) _Float16 Ct[32 * 132];  // epilogue transpose tile

    const int tid = threadIdx.x;
    const int w = tid >> 6, lane = tid & 63;
    const int g = lane >> 4, c = lane & 15;
    const int m0 = blockIdx.x * 128, n0 = blockIdx.y * 128;
    const int wm = (w & 1) * 64, wn = (w >> 1) * 64;
    const int srow = w * 32 + (lane >> 2);
    const int scol = (lane & 3) * 8;  // in halves

    f32x4 acc[4][4] = {};

    for (int k0 = 0; k0 < 1024; k0 += 32) {
        __syncthreads();
#pragma unroll
        for (int t = 0; t < 2; ++t) {
            int r = srow + t * 16;
            gl_lds16(A + (size_t)(m0 + r) * 1024 + k0 + scol, &At[(w * 2 + t) * 512]);
            gl_lds16(W + (size_t)(n0 + r) * 1024 + k0 + scol, &Bt[(w * 2 + t) * 512]);
        }
        __syncthreads();
        f16x8 af[4], bf[4];
#pragma unroll
        for (int mt = 0; mt < 4; ++mt) af[mt] = *(const f16x8*)&At[(wm + mt * 16 + c) * 32 + g * 8];
#pragma unroll
        for (int nt = 0; nt < 4; ++nt) bf[nt] = *(const f16x8*)&Bt[(wn + nt * 16 + c) * 32 + g * 8];
#pragma unroll
        for (int mt = 0; mt < 4; ++mt)
#pragma unroll
            for (int nt = 0; nt < 4; ++nt)
                acc[mt][nt] = MFMA16(af[mt], bf[nt], acc[mt][nt]);
    }

    if (z != 2) {
        _Float16* T = (z == 0) ? qT : kT;
        const float mulf = (z == 0) ? C1 : 1.0f;  // fold softmax scale into q
        __syncthreads();  // staging LDS done (At/Bt dead; Ct fresh)
#pragma unroll
        for (int mt = 0; mt < 4; ++mt) {
            // scatter acc into a [32 rows][132] f16 tile (rows = 2 bands of 16)
#pragma unroll
            for (int nt = 0; nt < 4; ++nt) {
                int colL = wn + nt * 16 + c;
                float bb = bias[n0 + colL];
#pragma unroll
                for (int i = 0; i < 4; ++i) {
                    int lr = (w & 1) * 16 + g * 4 + i;
                    Ct[lr * 132 + colL] = (_Float16)((acc[mt][nt][i] + bb) * mulf);
                }
            }
            __syncthreads();
            // gather rows, store coalesced f16x8 to the fragment pages
#pragma unroll
            for (int rep = 0; rep < 2; ++rep) {
                int eg = (tid >> 5) + rep * 8;  // 0..15: 8-col group
                int r = tid & 31;
                f16x8 vv = *(const f16x8*)&Ct[r * 132 + eg * 8];
                int mrow = m0 + (r >> 4) * 64 + mt * 16 + (r & 15);
                int colg = n0 + eg * 8;
                int hh = colg >> 6, dsub = colg & 63;
                int dc = dsub >> 4, hi2 = (dsub >> 3) & 1;
                int bbi = mrow >> 10, nn = mrow & 1023;
                size_t off;
                if (z == 0)
                    off = ((((size_t)(bbi * 16 + hh) * 32 + ((nn >> 5) & 31)) * 4 + dc) * 32 +
                           (nn & 31)) * 16 + hi2 * 8;
                else
                    off = (((((size_t)(bbi * 16 + hh) * 8 + (nn >> 7)) * 4 + ((nn >> 5) & 3)) * 4 +
                            dc) * 32 + (nn & 31)) * 16 + hi2 * 8;
                *(f16x8*)&T[off] = vv;
            }
            __syncthreads();
        }
    } else {
#pragma unroll
        for (int mt = 0; mt < 4; ++mt)
#pragma unroll
            for (int nt = 0; nt < 4; ++nt) {
                int col = n0 + wn + nt * 16 + c;
                int hh = col >> 6, dd = col & 63;
                int dh = dd >> 5, q5v = dd & 31;
                float bb = bias[col];
                int row0 = m0 + wm + mt * 16 + g * 4;
                int bbi = row0 >> 10, nn = row0 & 1023;
                int wa = nn >> 7, kt = (nn >> 5) & 3;
                int ks = (nn >> 4) & 1, hi2 = (nn >> 3) & 1, j0 = nn & 7;
                f16x4 pk;
#pragma unroll
                for (int i = 0; i < 4; ++i) pk[i] = (_Float16)(acc[mt][nt][i] + bb);
                size_t off = ((((((size_t)(bbi * 16 + hh) * 8 + wa) * 4 + kt) * 2 + dh) * 2 + ks) * 32 +
                              q5v) * 16 + hi2 * 8 + j0;
                *(f16x4*)&vT[off] = pk;
            }
    }
}

// ---------------------------------------------------------------------------
// fused attention v11: 512 threads (8 waves), fixed-role rotating buffers.
// vs v10: (1) ALL K tiles prefetched during previous PV (>=800cy cover; v10's
// K2/K3 had ~60cy); V_kt issued right after s_kt frees its buffer (>=500cy).
// (2) pack via cvt_pkrtz + v_permlane32_swap_b32 (no selects/shfl). (3) C1
// pre-folded into qT: exp2(s-pm) directly. (4) PV on unnormalized e right
// after pack (overlaps barrier+fixup); per-wave sc applied at O-reduce via
// sc_arr LDS; av scaled only for the aacc MFMAs.
// ---------------------------------------------------------------------------
__global__ __launch_bounds__(512, 2) void attn(
    const _Float16* __restrict__ qT, const _Float16* __restrict__ kT,
    const _Float16* __restrict__ vT, float* __restrict__ O,
    _Float16* __restrict__ part0, _Float16* __restrict__ part1) {
    extern __shared__ __align__(16) char smem[];
    float* Obuf = (float*)smem;                 // [8][2176] f32 = 69632
    float* red_m = (float*)(smem + 69632);      // [8][32]
    float* red_l = red_m + 256;                 // [8][32]
    float* sc_arr = red_l + 256;                // [8][33]

    const int tid = threadIdx.x, w = tid >> 6, lane = tid & 63;
    const int q5 = lane & 31, hi = lane >> 5;

    const int f = blockIdx.x;
    const int grp = f & 7, qt = f >> 3, q0 = qt * 32;
    const int chunk = grp & 1, b2 = grp >> 1;

    const int lofs = q5 * 16 + hi * 8;  // per-lane offset within a 1KB page

    // Bsel B-fragments: Bsel[ks](k,n) = (k == n&15 && n>>4 == ks)
    f16x8 bsel[2];
#pragma unroll
    for (int ks = 0; ks < 2; ++ks)
#pragma unroll
        for (int j = 0; j < 8; ++j)
            bsel[ks][j] = (hi * 8 + j == (q5 & 15) && (q5 >> 4) == ks)
                              ? (_Float16)1.0f : (_Float16)0.0f;

    f32x16 aacc[4] = {};

    // fixed-role buffers: b{A,B,C,D} hold K_kt -> V_kt -> K_kt' per pair
    f16x8 bA[4], bB[4], bC[4], bD[4], qf[4];

    // ---- prologue: K0..K3 + Q of pair 0 ----
    {
        const int m0p = b2 * 16 + chunk * 8;
        const int head = (m0p & 3) * 16 + (m0p >> 2);
        const _Float16* kb = kT + ((size_t)head * 8 + w) * 8192 + lofs;
        const _Float16* qb = qT + ((size_t)head * 32 + qt) * 2048 + lofs;
#pragma unroll
        for (int dc = 0; dc < 4; ++dc) {
            bA[dc] = *(const f16x8*)(kb + dc * 512);
            bB[dc] = *(const f16x8*)(kb + 2048 + dc * 512);
            bC[dc] = *(const f16x8*)(kb + 4096 + dc * 512);
            bD[dc] = *(const f16x8*)(kb + 6144 + dc * 512);
            qf[dc] = *(const f16x8*)(qb + dc * 512);
        }
    }

#pragma unroll 1
    for (int p = 0; p < 8; ++p) {
        const int m = b2 * 16 + chunk * 8 + p;
        const int head = (m & 3) * 16 + (m >> 2);
        const _Float16* vb = vT + ((size_t)head * 8 + w) * 8192 + lofs;
        const int mn = m + 1;  // p==7 reads valid-but-unused memory (head<=16)
        const int headn = (mn & 3) * 16 + (mn >> 2);
        const _Float16* kbn = kT + ((size_t)headn * 8 + w) * 8192 + lofs;
        const _Float16* qbn = qT + ((size_t)headn * 32 + qt) * 2048 + lofs;

        // ---- pipelined O-reduce of pair p-1, scaled by per-wave sc ----
        if (p) {
            int mp = m - 1; int bp = mp & 3, hp = mp >> 2;
            int qq = tid >> 4, dd = (tid & 15) * 4;
            f32x4 acc = {};
#pragma unroll
            for (int buf = 0; buf < 8; ++buf) {
                f32x4 v = *(f32x4*)&Obuf[buf * 2176 + qq * 68 + dd];
                float fw = sc_arr[buf * 33 + qq];
#pragma unroll
                for (int j = 0; j < 4; ++j) acc[j] += v[j] * fw;
            }
            *(f32x4*)(O + (size_t)bp * 1048576 + (size_t)(q0 + qq) * 1024 + hp * 64 + dd) = acc;
        }

        // ---- QK^T (K resident from prev-pair prefetch); V_kt issued as
        //      each K buffer frees ----
        f32x16 s0 = {}, s1 = {}, s2 = {}, s3 = {};
#pragma unroll
        for (int dc = 0; dc < 4; ++dc) s0 = MFMA32(bA[dc], qf[dc], s0);
#pragma unroll
        for (int i = 0; i < 4; ++i) bA[i] = *(const f16x8*)(vb + i * 512);           // V0
#pragma unroll
        for (int dc = 0; dc < 4; ++dc) s1 = MFMA32(bB[dc], qf[dc], s1);
#pragma unroll
        for (int i = 0; i < 4; ++i) bB[i] = *(const f16x8*)(vb + 2048 + i * 512);    // V1
#pragma unroll
        for (int dc = 0; dc < 4; ++dc) s2 = MFMA32(bC[dc], qf[dc], s2);
#pragma unroll
        for (int i = 0; i < 4; ++i) bC[i] = *(const f16x8*)(vb + 4096 + i * 512);    // V2
#pragma unroll
        for (int dc = 0; dc < 4; ++dc) s3 = MFMA32(bD[dc], qf[dc], s3);
#pragma unroll
        for (int i = 0; i < 4; ++i) bD[i] = *(const f16x8*)(vb + 6144 + i * 512);    // V3

        // ---- local (wave) max + exp + sum (C1 pre-folded into q) ----
        float pm = -3.0e38f;
#pragma unroll
        for (int r = 0; r < 16; ++r) {
            pm = fmaxf(pm, s0[r]); pm = fmaxf(pm, s1[r]);
            pm = fmaxf(pm, s2[r]); pm = fmaxf(pm, s3[r]);
        }
        pm = fmaxf(pm, __shfl_xor(pm, 32, 64));
        float l = 0.f;
#pragma unroll
        for (int r = 0; r < 16; ++r) {
            float e0 = exp2f(s0[r] - pm); s0[r] = e0;
            float e1 = exp2f(s1[r] - pm); s1[r] = e1;
            float e2 = exp2f(s2[r] - pm); s2[r] = e2;
            float e3 = exp2f(s3[r] - pm); s3[r] = e3;
            l += (e0 + e1) + (e2 + e3);
        }
        l += __shfl_xor(l, 32, 64);
        if (hi == 0) { red_m[w * 32 + q5] = pm; red_l[w * 32 + q5] = l; }

        // ---- pack e -> f16 A-fragments via cvt_pkrtz + permlane32_swap ----
        u32x4 av[4][2];
#define PACK_KT(SK, KT) do { \
            unsigned pw[8]; \
            _Pragma("unroll") \
            for (int r2 = 0; r2 < 8; ++r2) { \
                pw[r2] = __builtin_bit_cast( \
                    unsigned, __builtin_amdgcn_cvt_pkrtz(SK[2 * r2], SK[2 * r2 + 1])); \
            } \
            _Pragma("unroll") \
            for (int ks = 0; ks < 2; ++ks) { \
                unsigned a0 = pw[4 * ks + 0], b0 = pw[4 * ks + 2]; \
                unsigned a1 = pw[4 * ks + 1], b1 = pw[4 * ks + 3]; \
                asm volatile("v_permlane32_swap_b32 %0, %1" : "+v"(a0), "+v"(b0)); \
                asm volatile("v_permlane32_swap_b32 %0, %1" : "+v"(a1), "+v"(b1)); \
                u32x4 a; a[0] = a0; a[1] = a1; a[2] = b0; a[3] = b1; \
                av[KT][ks] = a; \
            } \
        } while (0)
        PACK_KT(s0, 0);
        PACK_KT(s1, 1);
        PACK_KT(s2, 2);
        PACK_KT(s3, 3);
#undef PACK_KT

        // ---- PV on unnormalized e (overlaps barrier+fixup); prefetch K'/Q' ----
        f32x16 o0 = {}, o1 = {};
#pragma unroll
        for (int ks = 0; ks < 2; ++ks) {
            f16x8 pa = __builtin_bit_cast(f16x8, av[0][ks]);
            o0 = MFMA32(pa, bA[ks], o0);
            o1 = MFMA32(pa, bA[2 + ks], o1);
        }
#pragma unroll
        for (int dc = 0; dc < 4; ++dc) bA[dc] = *(const f16x8*)(kbn + dc * 512);          // K0'
#pragma unroll
        for (int ks = 0; ks < 2; ++ks) {
            f16x8 pa = __builtin_bit_cast(f16x8, av[1][ks]);
            o0 = MFMA32(pa, bB[ks], o0);
            o1 = MFMA32(pa, bB[2 + ks], o1);
        }
#pragma unroll
        for (int dc = 0; dc < 4; ++dc) bB[dc] = *(const f16x8*)(kbn + 2048 + dc * 512);   // K1'
#pragma unroll
        for (int ks = 0; ks < 2; ++ks) {
            f16x8 pa = __builtin_bit_cast(f16x8, av[2][ks]);
            o0 = MFMA32(pa, bC[ks], o0);
            o1 = MFMA32(pa, bC[2 + ks], o1);
        }
#pragma unroll
        for (int dc = 0; dc < 4; ++dc) bC[dc] = *(const f16x8*)(kbn + 4096 + dc * 512);   // K2'
#pragma unroll
        for (int ks = 0; ks < 2; ++ks) {
            f16x8 pa = __builtin_bit_cast(f16x8, av[3][ks]);
            o0 = MFMA32(pa, bD[ks], o0);
            o1 = MFMA32(pa, bD[2 + ks], o1);
        }
#pragma unroll
        for (int dc = 0; dc < 4; ++dc) {
            bD[dc] = *(const f16x8*)(kbn + 6144 + dc * 512);                              // K3'
            qf[dc] = *(const f16x8*)(qbn + dc * 512);                                     // Q'
        }

        LGKM0_BARRIER;  // A — red_m/red_l visible; global loads stay in flight

        // ---- global fixup over 8 waves ----
        float mr[4], lr[4], M = -3.0e38f;
#pragma unroll
        for (int t = 0; t < 4; ++t) {
            int wv = hi * 4 + t;
            mr[t] = red_m[wv * 32 + q5];
            lr[t] = red_l[wv * 32 + q5];
            M = fmaxf(M, mr[t]);
        }
        M = fmaxf(M, __shfl_xor(M, 32, 64));
        float L = 0.f;
#pragma unroll
        for (int t = 0; t < 4; ++t) L += lr[t] * exp2f(mr[t] - M);
        L += __shfl_xor(L, 32, 64);
        const float sc = exp2f(pm - M) / L;
        if (hi == 0) sc_arr[w * 33 + q5] = sc;

        // ---- scale av (P = e*sc) for the avg accumulation ----
        {
            const _Float16 sch = (_Float16)sc;
            f16x8 scv;
#pragma unroll
            for (int j2 = 0; j2 < 8; ++j2) scv[j2] = sch;
#pragma unroll
            for (int kt = 0; kt < 4; ++kt)
#pragma unroll
                for (int ks = 0; ks < 2; ++ks)
                    av[kt][ks] = __builtin_bit_cast(
                        u32x4, __builtin_bit_cast(f16x8, av[kt][ks]) * scv);
        }
#pragma unroll
        for (int kt = 0; kt < 4; ++kt) {
            aacc[kt] = MFMA32(__builtin_bit_cast(f16x8, av[kt][0]), bsel[0], aacc[kt]);
            aacc[kt] = MFMA32(__builtin_bit_cast(f16x8, av[kt][1]), bsel[1], aacc[kt]);
        }

        // ---- O partials (unnormalized) to Obuf ----
        float* ob = Obuf + w * 2176;
#pragma unroll
        for (int r = 0; r < 16; ++r) {
            int qq = (r & 3) + 8 * (r >> 2) + 4 * hi;
            ob[qq * 68 + q5] = o0[r];
            ob[qq * 68 + 32 + q5] = o1[r];
        }
        LGKM0_BARRIER;  // C — Obuf + sc_arr visible; prefetches stay in flight
    }

    // ---- final reduce + store O for pair 7 (scaled) ----
    {
        int mp = b2 * 16 + chunk * 8 + 7; int bp = mp & 3, hp = mp >> 2;
        int qq = tid >> 4, dd = (tid & 15) * 4;
        f32x4 acc = {};
#pragma unroll
        for (int buf = 0; buf < 8; ++buf) {
            f32x4 v = *(f32x4*)&Obuf[buf * 2176 + qq * 68 + dd];
            float fw = sc_arr[buf * 33 + qq];
#pragma unroll
            for (int j = 0; j < 4; ++j) acc[j] += v[j] * fw;
        }
        *(f32x4*)(O + (size_t)bp * 1048576 + (size_t)(q0 + qq) * 1024 + hp * 64 + dd) = acc;
    }

    // ---- A_avg tail: non-atomic f16 partial stores (one writer/element) ----
    {
        _Float16* pb = (chunk ? part1 : part0) + ((size_t)b2 * 1024 + q0) * 1024;
#pragma unroll
        for (int kt = 0; kt < 4; ++kt) {
            int k = w * 128 + kt * 32 + q5;
#pragma unroll
            for (int r = 0; r < 16; ++r) {
                int qq = (r & 3) + 8 * (r >> 2) + 4 * hi;
                pb[(size_t)qq * 1024 + k] = (_Float16)aacc[kt][r];
            }
        }
    }
}

// ---------------------------------------------------------------------------
// A_avg = (part0 + part1) / 16
// ---------------------------------------------------------------------------
__global__ void add_avg(const _Float16* __restrict__ p0,
                        const _Float16* __restrict__ p1,
                        float* __restrict__ out) {
    int i = blockIdx.x * blockDim.x + threadIdx.x;  // groups of 8
    f16x8 a = ((const f16x8*)p0)[i];
    f16x8 b = ((const f16x8*)p1)[i];
    f32x4 r0, r1;
#pragma unroll
    for (int j = 0; j < 4; ++j) r0[j] = ((float)a[j] + (float)b[j]) * 0.0625f;
#pragma unroll
    for (int j = 0; j < 4; ++j) r1[j] = ((float)a[4 + j] + (float)b[4 + j]) * 0.0625f;
    *(f32x4*)&out[8 * i] = r0;
    *(f32x4*)&out[8 * i + 4] = r1;
}

// ---------------------------------------------------------------------------
extern "C" void kernel_launch(void* const* d_in, const int* in_sizes, int n_in,
                              void* d_out, int out_size, void* d_ws, size_t ws_size,
                              hipStream_t stream) {
    if (ws_size < ((size_t)46 << 20)) return;  // need 46 MB scratch

    const float* Q  = (const float*)d_in[0];
    const float* K  = (const float*)d_in[1];
    const float* Wq = (const float*)d_in[2];
    const float* bq = (const float*)d_in[3];
    const float* Wk = (const float*)d_in[4];
    const float* bk = (const float*)d_in[5];
    const float* Wv = (const float*)d_in[6];
    const float* bv = (const float*)d_in[7];

    char* ws = (char*)d_ws;
    _Float16* Qh  = (_Float16*)(ws);                      //  8 MB
    _Float16* Kh  = (_Float16*)(ws + ((size_t)8 << 20));  //  8 MB
    _Float16* Wqh = (_Float16*)(ws + ((size_t)16 << 20)); //  2 MB
    _Float16* Wkh = (_Float16*)(ws + ((size_t)18 << 20)); //  2 MB
    _Float16* Wvh = (_Float16*)(ws + ((size_t)20 << 20)); //  2 MB
    _Float16* qT  = (_Float16*)(ws + ((size_t)22 << 20)); //  8 MB (tiled, C1-scaled)
    _Float16* kT  = (_Float16*)(ws + ((size_t)30 << 20)); //  8 MB (tiled)
    _Float16* vT  = (_Float16*)(ws + ((size_t)38 << 20)); //  8 MB (tiled)
    // partials alias Qh/Kh (dead after proj_gemm)
    _Float16* part0 = (_Float16*)(ws);                     // 8 MB
    _Float16* part1 = (_Float16*)(ws + ((size_t)8 << 20)); // 8 MB

    float* O = (float*)d_out;
    float* Aavg = O + (size_t)4 * 1024 * 1024;

    // 1) convert inputs to fp16
    cvt_all<<<dim3(1441792 / 256), 256, 0, stream>>>(Q, K, Wq, Wk, Wv, Qh);

    // 2) three projection GEMMs (tiled outputs, vectorized epilogues)
    proj_gemm<<<dim3(32, 8, 3), 256, 0, stream>>>(Qh, Kh, Wqh, Wkh, Wvh,
                                                  bq, bk, bv, qT, kT, vT);

    // 3) fused attention: 256 blocks x 512 threads
    const int SMEM = 69632 + 1024 + 1024 + 8 * 33 * 4;  // 72736
    hipFuncSetAttribute((const void*)attn, hipFuncAttributeMaxDynamicSharedMemorySize, SMEM);
    attn<<<dim3(256), 512, SMEM, stream>>>(qT, kT, vT, O, part0, part1);

    // 4) A_avg = (part0 + part1) / 16
    add_avg<<<dim3(2048), 256, 0, stream>>>(part0, part1, Aavg);
}